// Round 14
// baseline (100.484 us; speedup 1.0000x reference)
//
#include <hip/hip_runtime.h>
#include <hip/hip_bf16.h>

#define T_TOK 256
#define C_DIM 1024
#define H_DIM 2048
#define E_NUM 8

typedef __attribute__((ext_vector_type(4))) float f32x4;
typedef __attribute__((ext_vector_type(8))) short short8;

// workspace layout (bytes)
#define WS_CNT     0
#define WS_LIST    1024
#define WS_XBF     16384                     // 512 KB
#define WS_HBUF    (1u<<20)                  // 1 MB bf16 (expert h)
#define WS_HSBUF   (2u<<20)                  // 1 MB bf16 (shared h)
#define WS_YS      (3u<<20)                  // 1 MB f32 (shared y)
#define WS_UPBF    (8u<<20)                  // 33.5 MB (E*H*C ush)
#define WS_GATEBF  (44u<<20)                 // 33.5 MB
#define WS_UPSBF   (80u<<20)                 // 4 MB (H*C ush)
#define WS_GATESBF (85u<<20)                 // 4 MB
#define WS_NEED    (90ull<<20)

#define N_EW  16777216ull                    // E*H*C
#define N_SW  2097152ull                     // H*C

__device__ __forceinline__ ushort f2bf(float f) {
    __hip_bfloat16 h = __float2bfloat16(f);
    return *reinterpret_cast<ushort*>(&h);
}

__device__ __forceinline__ ushort4 f2bf4(float4 v) {
    ushort4 r; r.x = f2bf(v.x); r.y = f2bf(v.y); r.z = f2bf(v.z); r.w = f2bf(v.w);
    return r;
}

__device__ __forceinline__ ushort4 f2bf4v(f32x4 v) {
    ushort4 r; r.x = f2bf(v[0]); r.y = f2bf(v[1]); r.z = f2bf(v[2]); r.w = f2bf(v[3]);
    return r;
}

__device__ __forceinline__ short8 pack8(float4 a, float4 b) {
    short8 s;
    s[0] = (short)f2bf(a.x); s[1] = (short)f2bf(a.y);
    s[2] = (short)f2bf(a.z); s[3] = (short)f2bf(a.w);
    s[4] = (short)f2bf(b.x); s[5] = (short)f2bf(b.y);
    s[6] = (short)f2bf(b.z); s[7] = (short)f2bf(b.w);
    return s;
}

// async global->LDS DMA, 16B/lane. LDS dest = wave-uniform base + lane*16.
__device__ __forceinline__ void gload16(const void* g, void* l) {
    __builtin_amdgcn_global_load_lds((const __attribute__((address_space(1))) void*)g,
                                     (__attribute__((address_space(3))) void*)l, 16, 0, 0);
}

#define MFMA(a, b, c) __builtin_amdgcn_mfma_f32_16x16x32_bf16((a), (b), (c), 0, 0, 0)

#define VMWAIT(N) do { asm volatile("s_waitcnt vmcnt(" #N ")" ::: "memory"); \
                       __builtin_amdgcn_sched_barrier(0); } while (0)
#define LGKWAIT() do { asm volatile("s_waitcnt lgkmcnt(0)" ::: "memory"); \
                       __builtin_amdgcn_sched_barrier(0); } while (0)
#define BAR() do { __builtin_amdgcn_s_barrier(); \
                   __builtin_amdgcn_sched_barrier(0); } while (0)

// linear f32 -> bf16 weight conversion (m13-style sequential sweep).
// 18432 blocks x 256 thr; thread gid converts 8 consecutive f32.
__global__ __launch_bounds__(256) void wprep(
    const float* __restrict__ up, const float* __restrict__ gate,
    const float* __restrict__ ups, const float* __restrict__ gates,
    ushort* __restrict__ upbf, ushort* __restrict__ gatebf,
    ushort* __restrict__ upsbf, ushort* __restrict__ gatesbf)
{
    size_t gid = (size_t)blockIdx.x * 256 + threadIdx.x;
    size_t base = gid * 8;
    const float* src; ushort* dst;
    if (base < N_EW)               { src = up    + base;                dst = upbf    + base; }
    else if (base < 2 * N_EW)      { src = gate  + (base - N_EW);       dst = gatebf  + (base - N_EW); }
    else if (base < 2 * N_EW + N_SW){ src = ups  + (base - 2 * N_EW);   dst = upsbf   + (base - 2 * N_EW); }
    else                           { src = gates + (base - 2 * N_EW - N_SW); dst = gatesbf + (base - 2 * N_EW - N_SW); }
    float4 a = *reinterpret_cast<const float4*>(src);
    float4 b = *reinterpret_cast<const float4*>(src + 4);
    *reinterpret_cast<short8*>(dst) = pack8(a, b);
}

// router + x->bf16 prep fused. 1 block per token.
__global__ __launch_bounds__(256) void router_kernel(
    const float* __restrict__ x, const float* __restrict__ router,
    int* __restrict__ cnt, int* __restrict__ list, ushort* __restrict__ xbf)
{
    const int t = blockIdx.x;
    const int tid = threadIdx.x;
    float4 xv = reinterpret_cast<const float4*>(x + (size_t)t * C_DIM)[tid];
    *reinterpret_cast<ushort4*>(xbf + (size_t)t * C_DIM + tid * 4) = f2bf4(xv);

    float p[E_NUM];
#pragma unroll
    for (int e = 0; e < E_NUM; e++) {
        float4 rv = reinterpret_cast<const float4*>(router + (size_t)e * C_DIM)[tid];
        p[e] = xv.x * rv.x + xv.y * rv.y + xv.z * rv.z + xv.w * rv.w;
    }
#pragma unroll
    for (int e = 0; e < E_NUM; e++) {
#pragma unroll
        for (int off = 32; off >= 1; off >>= 1)
            p[e] += __shfl_down(p[e], off, 64);
    }
    __shared__ float red[E_NUM][4];
    const int lane = tid & 63, wv = tid >> 6;
    if (lane == 0) {
#pragma unroll
        for (int e = 0; e < E_NUM; e++) red[e][wv] = p[e];
    }
    __syncthreads();
    if (tid == 0) {
        float best = -3.4e38f; int bi = 0;
#pragma unroll
        for (int e = 0; e < E_NUM; e++) {
            float v = red[e][0] + red[e][1] + red[e][2] + red[e][3];
            if (v > best) { best = v; bi = e; }
        }
        int pos = atomicAdd(&cnt[bi], 1);
        list[bi * T_TOK + pos] = t;
    }
}

// ug (bf16-weight path): BM=32 x BN=16, K=1024 in 4 chunks of 256 elems.
// All operands staged via gload_lds from bf16 (weights freshly written by
// wprep -> L3-resident). 2-barrier loop. grid (9, 128, 8), 32 KB LDS.
__global__ __launch_bounds__(256, 3) void ug_mfma_bf(
    const ushort* __restrict__ xbf, const ushort* __restrict__ upbf,
    const ushort* __restrict__ gatebf, const ushort* __restrict__ upsbf,
    const ushort* __restrict__ gatesbf,
    const int* __restrict__ cnt, const int* __restrict__ list,
    ushort* __restrict__ hbuf, ushort* __restrict__ hsbuf)
{
    const int e = blockIdx.x, by = blockIdx.y, tt = blockIdx.z;
    const bool sh = (e == E_NUM);
    const int n = sh ? T_TOK : cnt[e];
    if (tt * 32 >= n) return;
    const int tid = threadIdx.x, lane = tid & 63, wv = tid >> 6;
    const int lc = lane & 15, kg = lane >> 4;

    __shared__ __align__(16) char smem[32768];
    ushort* Xl  = (ushort*)smem;                 // 16 KB: 32 rows x 256 ush
    ushort* WuL = (ushort*)(smem + 16384);       // 8 KB: 16 rows x 256 ush
    ushort* WgL = (ushort*)(smem + 24576);       // 8 KB
    __shared__ int toks_s[32];

    if (tid < 32) {
        int t = tt * 32 + tid;
        toks_s[tid] = (t < n) ? (sh ? t : list[e * T_TOK + t]) : -1;
    }
    __syncthreads();

    const int h0 = by * 16;
    const ushort* __restrict__ ubase = (sh ? upsbf   : upbf   + (size_t)e * H_DIM * C_DIM) + (size_t)h0 * C_DIM;
    const ushort* __restrict__ gbase = (sh ? gatesbf : gatebf + (size_t)e * H_DIM * C_DIM) + (size_t)h0 * C_DIM;

    // weights: 8 instrs each (rows 2j,2j+1 per instr), 2/wave per matrix.
#define W_STAGE(tc) do { _Pragma("unroll") for (int i = 0; i < 4; i++) { \
        int j_ = wv * 2 + (i & 1); \
        const ushort* b_ = (i < 2) ? ubase : gbase; \
        ushort* L_ = (i < 2) ? WuL : WgL; \
        int row_ = 2 * j_ + (lane >> 5); \
        int p_ = lane & 31; \
        int su_ = (p_ & ~7) | ((p_ ^ row_) & 7); \
        gload16(b_ + (size_t)row_ * C_DIM + (tc) * 256 + su_ * 8, (void*)(L_ + j_ * 512)); \
    } } while (0)

#define X_STAGE(tc) do { _Pragma("unroll") for (int i = 0; i < 4; i++) { \
        int j_ = wv * 4 + i; \
        int row_ = 2 * j_ + (lane >> 5); \
        int p_ = lane & 31; \
        int su_ = (p_ & ~7) | ((p_ ^ row_) & 7); \
        int tok_ = toks_s[row_]; if (tok_ < 0) tok_ = 0; \
        gload16(xbf + (size_t)tok_ * C_DIM + (tc) * 256 + su_ * 8, (void*)(Xl + j_ * 512)); \
    } } while (0)

    f32x4 au0 = {0,0,0,0}, au1 = {0,0,0,0}, ag0 = {0,0,0,0}, ag1 = {0,0,0,0};
#define COMPUTE() do { _Pragma("unroll") for (int k32 = 0; k32 < 2; k32++) { \
        int ku_ = wv * 8 + k32 * 4 + kg; \
        int up_ = (ku_ & ~7) | ((ku_ ^ lc) & 7); \
        short8 a0_ = *reinterpret_cast<const short8*>(Xl + lc * 256 + up_ * 8); \
        short8 a1_ = *reinterpret_cast<const short8*>(Xl + (16 + lc) * 256 + up_ * 8); \
        short8 bu_ = *reinterpret_cast<const short8*>(WuL + lc * 256 + up_ * 8); \
        short8 bg_ = *reinterpret_cast<const short8*>(WgL + lc * 256 + up_ * 8); \
        au0 = MFMA(a0_, bu_, au0); au1 = MFMA(a1_, bu_, au1); \
        ag0 = MFMA(a0_, bg_, ag0); ag1 = MFMA(a1_, bg_, ag1); \
    } } while (0)

#pragma unroll
    for (int t = 0; t < 4; t++) {
        X_STAGE(t);
        W_STAGE(t);
        __syncthreads();            // drain: all staging visible
        COMPUTE();
        __syncthreads();            // all waves done reading
    }
#undef W_STAGE
#undef X_STAGE
#undef COMPUTE

    // epilogue: cross-wave K reduce (alias smem) + silu + store
    f32x4* red = (f32x4*)smem;               // [4 wv][4 frag][64 lane] = 16 KB
    red[(wv * 4 + 0) * 64 + lane] = au0;
    red[(wv * 4 + 1) * 64 + lane] = au1;
    red[(wv * 4 + 2) * 64 + lane] = ag0;
    red[(wv * 4 + 3) * 64 + lane] = ag1;
    __syncthreads();
    if (tid < 128) {
        const int m = tid >> 6, ln = tid & 63, lc_ = ln & 15, kg_ = ln >> 4;
        f32x4 su = red[(0 + m) * 64 + ln];
        su += red[(4 + m) * 64 + ln];
        su += red[(8 + m) * 64 + ln];
        su += red[(12 + m) * 64 + ln];
        f32x4 sg = red[(2 + m) * 64 + ln];
        sg += red[(6 + m) * 64 + ln];
        sg += red[(10 + m) * 64 + ln];
        sg += red[(14 + m) * 64 + ln];
        ushort* __restrict__ outp = sh ? hsbuf : hbuf;
#pragma unroll
        for (int j = 0; j < 4; j++) {
            int tok = toks_s[m * 16 + kg_ * 4 + j];
            if (tok >= 0) {
                float g = sg[j], u = su[j];
                outp[(size_t)tok * H_DIM + h0 + lc_] = f2bf(u * (g / (1.f + __expf(-g))));
            }
        }
    }
}

// ug fallback (R12 f32-weight path) — used only if ws_size < WS_NEED.
__global__ __launch_bounds__(256, 3) void ug_mfma_direct(
    const ushort* __restrict__ xbf, const float* __restrict__ up, const float* __restrict__ gate,
    const float* __restrict__ w_up_s, const float* __restrict__ w_gate_s,
    const int* __restrict__ cnt, const int* __restrict__ list,
    ushort* __restrict__ hbuf, ushort* __restrict__ hsbuf)
{
    const int e = blockIdx.x, by = blockIdx.y, tt = blockIdx.z;
    const bool sh = (e == E_NUM);
    const int n = sh ? T_TOK : cnt[e];
    if (tt * 32 >= n) return;
    const int tid = threadIdx.x, lane = tid & 63, wv = tid >> 6;
    const int lc = lane & 15, kg = lane >> 4;

    __shared__ __align__(16) char smem[32768];
    ushort* Xl  = (ushort*)smem;
    ushort* WuL = (ushort*)(smem + 16384);
    ushort* WgL = (ushort*)(smem + 24576);
    __shared__ int toks_s[32];

    if (tid < 32) {
        int t = tt * 32 + tid;
        toks_s[tid] = (t < n) ? (sh ? t : list[e * T_TOK + t]) : -1;
    }
    __syncthreads();

    const int h0 = by * 16;
    const float* __restrict__ ubase = (sh ? w_up_s   : up   + (size_t)e * H_DIM * C_DIM) + (size_t)h0 * C_DIM;
    const float* __restrict__ gbase = (sh ? w_gate_s : gate + (size_t)e * H_DIM * C_DIM) + (size_t)h0 * C_DIM;

    f32x4 wreg[8];
#define W_LOAD(tc) do { _Pragma("unroll") for (int i = 0; i < 8; i++) { \
        int row_ = wv * 4 + (i & 3); \
        const float* b_ = (i < 4) ? ubase : gbase; \
        wreg[i] = *reinterpret_cast<const f32x4*>(b_ + (size_t)row_ * C_DIM + (tc) * 256 + lane * 4); \
    } } while (0)

#define W_WRITE() do { _Pragma("unroll") for (int i = 0; i < 8; i++) { \
        int row_ = wv * 4 + (i & 3); \
        ushort* WL_ = (i < 4) ? WuL : WgL; \
        int pos_ = ((lane >> 1) & ~7) | (((lane >> 1) ^ row_) & 7); \
        *reinterpret_cast<ushort4*>(WL_ + row_ * 256 + pos_ * 8 + (lane & 1) * 4) = f2bf4v(wreg[i]); \
    } } while (0)

#define X_STAGE(tc) do { _Pragma("unroll") for (int i = 0; i < 4; i++) { \
        int j_ = wv * 4 + i; \
        int row_ = 2 * j_ + (lane >> 5); \
        int p_ = lane & 31; \
        int su_ = (p_ & ~7) | ((p_ ^ row_) & 7); \
        int tok_ = toks_s[row_]; if (tok_ < 0) tok_ = 0; \
        gload16(xbf + (size_t)tok_ * C_DIM + (tc) * 256 + su_ * 8, (void*)(Xl + j_ * 512)); \
    } } while (0)

    f32x4 au0 = {0,0,0,0}, au1 = {0,0,0,0}, ag0 = {0,0,0,0}, ag1 = {0,0,0,0};
#define COMPUTE() do { _Pragma("unroll") for (int k32 = 0; k32 < 2; k32++) { \
        int ku_ = wv * 8 + k32 * 4 + kg; \
        int up_ = (ku_ & ~7) | ((ku_ ^ lc) & 7); \
        short8 a0_ = *reinterpret_cast<const short8*>(Xl + lc * 256 + up_ * 8); \
        short8 a1_ = *reinterpret_cast<const short8*>(Xl + (16 + lc) * 256 + up_ * 8); \
        short8 bu_ = *reinterpret_cast<const short8*>(WuL + lc * 256 + up_ * 8); \
        short8 bg_ = *reinterpret_cast<const short8*>(WgL + lc * 256 + up_ * 8); \
        au0 = MFMA(a0_, bu_, au0); au1 = MFMA(a1_, bu_, au1); \
        ag0 = MFMA(a0_, bg_, ag0); ag1 = MFMA(a1_, bg_, ag1); \
    } } while (0)

    W_LOAD(0);
#pragma unroll
    for (int t = 0; t < 4; t++) {
        X_STAGE(t);
        W_WRITE();
        if (t < 3) W_LOAD(t + 1);
        __syncthreads();
        COMPUTE();
        __syncthreads();
    }
#undef W_LOAD
#undef W_WRITE
#undef X_STAGE
#undef COMPUTE

    f32x4* red = (f32x4*)smem;
    red[(wv * 4 + 0) * 64 + lane] = au0;
    red[(wv * 4 + 1) * 64 + lane] = au1;
    red[(wv * 4 + 2) * 64 + lane] = ag0;
    red[(wv * 4 + 3) * 64 + lane] = ag1;
    __syncthreads();
    if (tid < 128) {
        const int m = tid >> 6, ln = tid & 63, lc_ = ln & 15, kg_ = ln >> 4;
        f32x4 su = red[(0 + m) * 64 + ln];
        su += red[(4 + m) * 64 + ln];
        su += red[(8 + m) * 64 + ln];
        su += red[(12 + m) * 64 + ln];
        f32x4 sg = red[(2 + m) * 64 + ln];
        sg += red[(6 + m) * 64 + ln];
        sg += red[(10 + m) * 64 + ln];
        sg += red[(14 + m) * 64 + ln];
        ushort* __restrict__ outp = sh ? hsbuf : hbuf;
#pragma unroll
        for (int j = 0; j < 4; j++) {
            int tok = toks_s[m * 16 + kg_ * 4 + j];
            if (tok >= 0) {
                float g = sg[j], u = su[j];
                outp[(size_t)tok * H_DIM + h0 + lc_] = f2bf(u * (g / (1.f + __expf(-g))));
            }
        }
    }
}

// down: UNCHANGED (passed four times; cache-served).
__global__ __launch_bounds__(256, 2) void down_mfma(
    const float* __restrict__ dwn, const float* __restrict__ w_down_s,
    const ushort* __restrict__ hbuf, const ushort* __restrict__ hsbuf,
    const int* __restrict__ cnt, const int* __restrict__ list,
    float* __restrict__ y, float* __restrict__ yspart)
{
    const int e = blockIdx.x, by = blockIdx.y, tt = blockIdx.z;
    const bool sh = (e == E_NUM);
    const int n = sh ? T_TOK : cnt[e];
    if (tt * 32 >= n) return;
    const int tid = threadIdx.x, lane = tid & 63, wv = tid >> 6;
    const int lc = lane & 15, kg = lane >> 4;

    __shared__ __align__(16) char smem[49152];
    ushort* Hl  = (ushort*)smem;
    ushort* WdL = (ushort*)(smem + 32768);
    __shared__ int toks_s[32];

    if (tid < 32) {
        int t = tt * 32 + tid;
        toks_s[tid] = (t < n) ? (sh ? t : list[e * T_TOK + t]) : -1;
    }
    __syncthreads();

    const int c0 = by * 16;
    const float* __restrict__ dbase = (sh ? w_down_s : dwn + (size_t)e * C_DIM * H_DIM) + (size_t)c0 * H_DIM;
    const ushort* __restrict__ hin = sh ? hsbuf : hbuf;

    float4 wreg[4];
#define W_LOAD(tc) do { _Pragma("unroll") for (int i = 0; i < 4; i++) { \
        int row_ = wv * 4 + i; \
        wreg[i] = *reinterpret_cast<const float4*>(dbase + (size_t)row_ * H_DIM + (tc) * 256 + lane * 4); \
    } } while (0)

#define W_WRITE(bf) do { _Pragma("unroll") for (int i = 0; i < 4; i++) { \
        int row_ = wv * 4 + i; \
        int pos_ = ((lane >> 1) & ~7) | (((lane >> 1) ^ row_) & 7); \
        *reinterpret_cast<ushort4*>(WdL + (bf) * 4096 + row_ * 256 + pos_ * 8 + (lane & 1) * 4) = f2bf4(wreg[i]); \
    } } while (0)

#define H_STAGE(tc, bf) do { _Pragma("unroll") for (int i = 0; i < 4; i++) { \
        int j_ = wv * 4 + i; \
        int row_ = 2 * j_ + (lane >> 5); \
        int p_ = lane & 31; \
        int su_ = (p_ & ~7) | ((p_ ^ row_) & 7); \
        int tok_ = toks_s[row_]; if (tok_ < 0) tok_ = 0; \
        gload16(hin + (size_t)tok_ * H_DIM + (tc) * 256 + su_ * 8, (void*)(Hl + (bf) * 8192 + j_ * 512)); \
    } } while (0)

    f32x4 ac0 = {0,0,0,0}, ac1 = {0,0,0,0};
#define COMPUTE(bf) do { _Pragma("unroll") for (int k32 = 0; k32 < 2; k32++) { \
        int ku_ = wv * 8 + k32 * 4 + kg; \
        int up_ = (ku_ & ~7) | ((ku_ ^ lc) & 7); \
        short8 a0_ = *reinterpret_cast<const short8*>(Hl + (bf) * 8192 + lc * 256 + up_ * 8); \
        short8 a1_ = *reinterpret_cast<const short8*>(Hl + (bf) * 8192 + (16 + lc) * 256 + up_ * 8); \
        short8 bd_ = *reinterpret_cast<const short8*>(WdL + (bf) * 4096 + lc * 256 + up_ * 8); \
        ac0 = MFMA(a0_, bd_, ac0); ac1 = MFMA(a1_, bd_, ac1); \
    } } while (0)

    W_LOAD(0);
    H_STAGE(0, 0);
    VMWAIT(4);
    W_WRITE(0);
    W_LOAD(1);
    H_STAGE(1, 1);
    LGKWAIT();
    VMWAIT(8);
    BAR();

#pragma unroll
    for (int t = 0; t < 8; t++) {
        COMPUTE(t & 1);
        if (t < 7) {
            VMWAIT(4);
            W_WRITE((t + 1) & 1);
            if (t < 6) W_LOAD(t + 2);
            LGKWAIT();
        }
        BAR();
        if (t < 6) H_STAGE(t + 2, t & 1);
        if (t < 6)      { VMWAIT(8); }
        else if (t == 6){ VMWAIT(0); }
        BAR();
    }

    f32x4* red = (f32x4*)smem;
    red[(wv * 2 + 0) * 64 + lane] = ac0;
    red[(wv * 2 + 1) * 64 + lane] = ac1;
    __syncthreads();
    if (tid < 128) {
        const int m = tid >> 6, ln = tid & 63, lc_ = ln & 15, kg_ = ln >> 4;
        f32x4 s = red[(0 + m) * 64 + ln];
        s += red[(2 + m) * 64 + ln];
        s += red[(4 + m) * 64 + ln];
        s += red[(6 + m) * 64 + ln];
        float* __restrict__ outp = sh ? yspart : y;
#pragma unroll
        for (int j = 0; j < 4; j++) {
            int tok = toks_s[m * 16 + kg_ * 4 + j];
            if (tok >= 0) outp[(size_t)tok * C_DIM + c0 + lc_] = s[j];
        }
    }
#undef W_LOAD
#undef W_WRITE
#undef H_STAGE
#undef COMPUTE
}

__global__ __launch_bounds__(256) void add_kernel(float* __restrict__ y, const float* __restrict__ ys)
{
    int i = blockIdx.x * 256 + threadIdx.x;
    float4 a = reinterpret_cast<float4*>(y)[i];
    float4 b = reinterpret_cast<const float4*>(ys)[i];
    a.x += b.x; a.y += b.y; a.z += b.z; a.w += b.w;
    reinterpret_cast<float4*>(y)[i] = a;
}

extern "C" void kernel_launch(void* const* d_in, const int* in_sizes, int n_in,
                              void* d_out, int out_size, void* d_ws, size_t ws_size,
                              hipStream_t stream)
{
    const float* x        = (const float*)d_in[0];
    const float* up       = (const float*)d_in[1];
    const float* gate     = (const float*)d_in[2];
    const float* dwn      = (const float*)d_in[3];
    const float* router   = (const float*)d_in[4];
    const float* w_up_s   = (const float*)d_in[5];
    const float* w_gate_s = (const float*)d_in[6];
    const float* w_down_s = (const float*)d_in[7];

    char* ws = (char*)d_ws;
    int* cnt       = (int*)(ws + WS_CNT);
    int* list      = (int*)(ws + WS_LIST);
    ushort* xbf    = (ushort*)(ws + WS_XBF);
    ushort* hbuf   = (ushort*)(ws + WS_HBUF);
    ushort* hsbuf  = (ushort*)(ws + WS_HSBUF);
    float* yspart  = (float*)(ws + WS_YS);
    float* y = (float*)d_out;

    hipMemsetAsync(cnt, 0, E_NUM * sizeof(int), stream);
    router_kernel<<<T_TOK, 256, 0, stream>>>(x, router, cnt, list, xbf);

    if (ws_size >= WS_NEED) {
        ushort* upbf    = (ushort*)(ws + WS_UPBF);
        ushort* gatebf  = (ushort*)(ws + WS_GATEBF);
        ushort* upsbf   = (ushort*)(ws + WS_UPSBF);
        ushort* gatesbf = (ushort*)(ws + WS_GATESBF);
        wprep<<<18432, 256, 0, stream>>>(up, gate, w_up_s, w_gate_s,
                                         upbf, gatebf, upsbf, gatesbf);
        ug_mfma_bf<<<dim3(E_NUM + 1, H_DIM / 16, 8), 256, 0, stream>>>(
            xbf, upbf, gatebf, upsbf, gatesbf, cnt, list, hbuf, hsbuf);
    } else {
        ug_mfma_direct<<<dim3(E_NUM + 1, H_DIM / 16, 8), 256, 0, stream>>>(
            xbf, up, gate, w_up_s, w_gate_s, cnt, list, hbuf, hsbuf);
    }

    down_mfma<<<dim3(E_NUM + 1, C_DIM / 16, 8), 256, 0, stream>>>(
        dwn, w_down_s, hbuf, hsbuf, cnt, list, y, yspart);
    add_kernel<<<(T_TOK * C_DIM / 4) / 256, 256, 0, stream>>>(y, yspart);
}

// Round 15
// 86.563 us; speedup vs baseline: 1.1608x; 1.1608x over previous
//
#include <hip/hip_runtime.h>
#include <hip/hip_bf16.h>

#define T_TOK 256
#define C_DIM 1024
#define H_DIM 2048
#define E_NUM 8

typedef __attribute__((ext_vector_type(4))) float f32x4;
typedef __attribute__((ext_vector_type(8))) short short8;

// workspace layout (bytes)
#define WS_CNT    0
#define WS_LIST   1024
#define WS_XBF    16384                      // 512 KB
#define WS_HBUF   (1u<<20)                   // 1 MB bf16 (expert h)
#define WS_HSBUF  (2u<<20)                   // 1 MB bf16 (shared h)
#define WS_YS     (3u<<20)                   // 1 MB f32 (shared y)

__device__ __forceinline__ ushort f2bf(float f) {
    __hip_bfloat16 h = __float2bfloat16(f);
    return *reinterpret_cast<ushort*>(&h);
}

__device__ __forceinline__ ushort4 f2bf4(float4 v) {
    ushort4 r; r.x = f2bf(v.x); r.y = f2bf(v.y); r.z = f2bf(v.z); r.w = f2bf(v.w);
    return r;
}

__device__ __forceinline__ ushort4 f2bf4v(f32x4 v) {
    ushort4 r; r.x = f2bf(v[0]); r.y = f2bf(v[1]); r.z = f2bf(v[2]); r.w = f2bf(v[3]);
    return r;
}

// async global->LDS DMA, 16B/lane. LDS dest = wave-uniform base + lane*16.
__device__ __forceinline__ void gload16(const void* g, void* l) {
    __builtin_amdgcn_global_load_lds((const __attribute__((address_space(1))) void*)g,
                                     (__attribute__((address_space(3))) void*)l, 16, 0, 0);
}

#define MFMA(a, b, c) __builtin_amdgcn_mfma_f32_16x16x32_bf16((a), (b), (c), 0, 0, 0)

#define VMWAIT(N) do { asm volatile("s_waitcnt vmcnt(" #N ")" ::: "memory"); \
                       __builtin_amdgcn_sched_barrier(0); } while (0)
#define LGKWAIT() do { asm volatile("s_waitcnt lgkmcnt(0)" ::: "memory"); \
                       __builtin_amdgcn_sched_barrier(0); } while (0)
#define BAR() do { __builtin_amdgcn_s_barrier(); \
                   __builtin_amdgcn_sched_barrier(0); } while (0)

// router + x->bf16 prep fused. 1 block per token.
__global__ __launch_bounds__(256) void router_kernel(
    const float* __restrict__ x, const float* __restrict__ router,
    int* __restrict__ cnt, int* __restrict__ list, ushort* __restrict__ xbf)
{
    const int t = blockIdx.x;
    const int tid = threadIdx.x;
    float4 xv = reinterpret_cast<const float4*>(x + (size_t)t * C_DIM)[tid];
    *reinterpret_cast<ushort4*>(xbf + (size_t)t * C_DIM + tid * 4) = f2bf4(xv);

    float p[E_NUM];
#pragma unroll
    for (int e = 0; e < E_NUM; e++) {
        float4 rv = reinterpret_cast<const float4*>(router + (size_t)e * C_DIM)[tid];
        p[e] = xv.x * rv.x + xv.y * rv.y + xv.z * rv.z + xv.w * rv.w;
    }
#pragma unroll
    for (int e = 0; e < E_NUM; e++) {
#pragma unroll
        for (int off = 32; off >= 1; off >>= 1)
            p[e] += __shfl_down(p[e], off, 64);
    }
    __shared__ float red[E_NUM][4];
    const int lane = tid & 63, wv = tid >> 6;
    if (lane == 0) {
#pragma unroll
        for (int e = 0; e < E_NUM; e++) red[e][wv] = p[e];
    }
    __syncthreads();
    if (tid == 0) {
        float best = -3.4e38f; int bi = 0;
#pragma unroll
        for (int e = 0; e < E_NUM; e++) {
            float v = red[e][0] + red[e][1] + red[e][2] + red[e][3];
            if (v > best) { best = v; bi = e; }
        }
        int pos = atomicAdd(&cnt[bi], 1);
        list[bi * T_TOK + pos] = t;
    }
}

// ug: BM=32 tokens x BN=16 h-rows, K=1024 in 4 chunks of 256 f32.
// Weights: plain page-linear reads (1KB of one row per instr) -> regs ->
// bf16 -> swizzled ds_write. x: gload_lds, pre-swizzled source.
// Sync: __syncthreads() only (race-free; R10's counted vmcnt raced).
// grid (9 [8=shared], H/16=128, 8 token-tiles), block 256, 32 KB LDS.
__global__ __launch_bounds__(256, 3) void ug_mfma(
    const ushort* __restrict__ xbf, const float* __restrict__ up, const float* __restrict__ gate,
    const float* __restrict__ w_up_s, const float* __restrict__ w_gate_s,
    const int* __restrict__ cnt, const int* __restrict__ list,
    ushort* __restrict__ hbuf, ushort* __restrict__ hsbuf)
{
    const int e = blockIdx.x, by = blockIdx.y, tt = blockIdx.z;
    const bool sh = (e == E_NUM);
    const int n = sh ? T_TOK : cnt[e];
    if (tt * 32 >= n) return;
    const int tid = threadIdx.x, lane = tid & 63, wv = tid >> 6;
    const int lc = lane & 15, kg = lane >> 4;

    __shared__ __align__(16) char smem[32768];
    ushort* Xl  = (ushort*)smem;                 // 16 KB: 32 rows x 256 ush
    ushort* WuL = (ushort*)(smem + 16384);       // 8 KB: 16 rows x 256 ush
    ushort* WgL = (ushort*)(smem + 24576);       // 8 KB
    __shared__ int toks_s[32];

    if (tid < 32) {
        int t = tt * 32 + tid;
        toks_s[tid] = (t < n) ? (sh ? t : list[e * T_TOK + t]) : -1;
    }
    __syncthreads();

    const int h0 = by * 16;
    const float* __restrict__ ubase = (sh ? w_up_s   : up   + (size_t)e * H_DIM * C_DIM) + (size_t)h0 * C_DIM;
    const float* __restrict__ gbase = (sh ? w_gate_s : gate + (size_t)e * H_DIM * C_DIM) + (size_t)h0 * C_DIM;

    f32x4 wreg[8];
    // 8 loads/wave: i<4 -> Wu row wv*4+i, i>=4 -> Wg. 1KB contiguous per instr.
#define W_LOAD(tc) do { _Pragma("unroll") for (int i = 0; i < 8; i++) { \
        int row_ = wv * 4 + (i & 3); \
        const float* b_ = (i < 4) ? ubase : gbase; \
        wreg[i] = *reinterpret_cast<const f32x4*>(b_ + (size_t)row_ * C_DIM + (tc) * 256 + lane * 4); \
    } } while (0)

#define W_WRITE() do { _Pragma("unroll") for (int i = 0; i < 8; i++) { \
        int row_ = wv * 4 + (i & 3); \
        ushort* WL_ = (i < 4) ? WuL : WgL; \
        int pos_ = ((lane >> 1) & ~7) | (((lane >> 1) ^ row_) & 7); \
        *reinterpret_cast<ushort4*>(WL_ + row_ * 256 + pos_ * 8 + (lane & 1) * 4) = f2bf4v(wreg[i]); \
    } } while (0)

#define X_STAGE(tc) do { _Pragma("unroll") for (int i = 0; i < 4; i++) { \
        int j_ = wv * 4 + i; \
        int row_ = 2 * j_ + (lane >> 5); \
        int p_ = lane & 31; \
        int su_ = (p_ & ~7) | ((p_ ^ row_) & 7); \
        int tok_ = toks_s[row_]; if (tok_ < 0) tok_ = 0; \
        gload16(xbf + (size_t)tok_ * C_DIM + (tc) * 256 + su_ * 8, (void*)(Xl + j_ * 512)); \
    } } while (0)

    f32x4 au0 = {0,0,0,0}, au1 = {0,0,0,0}, ag0 = {0,0,0,0}, ag1 = {0,0,0,0};
#define COMPUTE() do { _Pragma("unroll") for (int k32 = 0; k32 < 2; k32++) { \
        int ku_ = wv * 8 + k32 * 4 + kg; \
        int up_ = (ku_ & ~7) | ((ku_ ^ lc) & 7); \
        short8 a0_ = *reinterpret_cast<const short8*>(Xl + lc * 256 + up_ * 8); \
        short8 a1_ = *reinterpret_cast<const short8*>(Xl + (16 + lc) * 256 + up_ * 8); \
        short8 bu_ = *reinterpret_cast<const short8*>(WuL + lc * 256 + up_ * 8); \
        short8 bg_ = *reinterpret_cast<const short8*>(WgL + lc * 256 + up_ * 8); \
        au0 = MFMA(a0_, bu_, au0); au1 = MFMA(a1_, bu_, au1); \
        ag0 = MFMA(a0_, bg_, ag0); ag1 = MFMA(a1_, bg_, ag1); \
    } } while (0)

    W_LOAD(0);
#pragma unroll
    for (int t = 0; t < 4; t++) {
        X_STAGE(t);                 // async into Xl (safe: past prev trailing barrier)
        W_WRITE();                  // compiler waits on wreg(t) loads, packs, ds_write
        if (t < 3) W_LOAD(t + 1);   // next W chunk issued; drains at the barrier
        __syncthreads();            // full drain: X + W writes visible to all waves
        COMPUTE();
        __syncthreads();            // all waves done reading Xl/WuL/WgL
    }
#undef W_LOAD
#undef W_WRITE
#undef X_STAGE
#undef COMPUTE

    // epilogue: cross-wave K reduce (alias Xl region) + silu + store
    f32x4* red = (f32x4*)smem;               // [4 wv][4 frag][64 lane] = 16 KB
    red[(wv * 4 + 0) * 64 + lane] = au0;
    red[(wv * 4 + 1) * 64 + lane] = au1;
    red[(wv * 4 + 2) * 64 + lane] = ag0;
    red[(wv * 4 + 3) * 64 + lane] = ag1;
    __syncthreads();
    if (tid < 128) {
        const int m = tid >> 6, ln = tid & 63, lc_ = ln & 15, kg_ = ln >> 4;
        f32x4 su = red[(0 + m) * 64 + ln];
        su += red[(4 + m) * 64 + ln];
        su += red[(8 + m) * 64 + ln];
        su += red[(12 + m) * 64 + ln];
        f32x4 sg = red[(2 + m) * 64 + ln];
        sg += red[(6 + m) * 64 + ln];
        sg += red[(10 + m) * 64 + ln];
        sg += red[(14 + m) * 64 + ln];
        ushort* __restrict__ outp = sh ? hsbuf : hbuf;
#pragma unroll
        for (int j = 0; j < 4; j++) {
            int tok = toks_s[m * 16 + kg_ * 4 + j];
            if (tok >= 0) {
                float g = sg[j], u = su[j];
                outp[(size_t)tok * H_DIM + h0 + lc_] = f2bf(u * (g / (1.f + __expf(-g))));
            }
        }
    }
}

// down: BM=32 tokens x BN=16 c-rows, K=2048 in 8 chunks of 256 f32.
// UNCHANGED (passed five times; cache-served).
__global__ __launch_bounds__(256, 2) void down_mfma(
    const float* __restrict__ dwn, const float* __restrict__ w_down_s,
    const ushort* __restrict__ hbuf, const ushort* __restrict__ hsbuf,
    const int* __restrict__ cnt, const int* __restrict__ list,
    float* __restrict__ y, float* __restrict__ yspart)
{
    const int e = blockIdx.x, by = blockIdx.y, tt = blockIdx.z;
    const bool sh = (e == E_NUM);
    const int n = sh ? T_TOK : cnt[e];
    if (tt * 32 >= n) return;
    const int tid = threadIdx.x, lane = tid & 63, wv = tid >> 6;
    const int lc = lane & 15, kg = lane >> 4;

    __shared__ __align__(16) char smem[49152];
    ushort* Hl  = (ushort*)smem;                 // 2 bufs x 32 rows x 256 ush (32 KB)
    ushort* WdL = (ushort*)(smem + 32768);       // 2 bufs x 16 rows x 256 ush (16 KB)
    __shared__ int toks_s[32];

    if (tid < 32) {
        int t = tt * 32 + tid;
        toks_s[tid] = (t < n) ? (sh ? t : list[e * T_TOK + t]) : -1;
    }
    __syncthreads();

    const int c0 = by * 16;
    const float* __restrict__ dbase = (sh ? w_down_s : dwn + (size_t)e * C_DIM * H_DIM) + (size_t)c0 * H_DIM;
    const ushort* __restrict__ hin = sh ? hsbuf : hbuf;

    float4 wreg[4];
#define W_LOAD(tc) do { _Pragma("unroll") for (int i = 0; i < 4; i++) { \
        int row_ = wv * 4 + i; \
        wreg[i] = *reinterpret_cast<const float4*>(dbase + (size_t)row_ * H_DIM + (tc) * 256 + lane * 4); \
    } } while (0)

#define W_WRITE(bf) do { _Pragma("unroll") for (int i = 0; i < 4; i++) { \
        int row_ = wv * 4 + i; \
        int pos_ = ((lane >> 1) & ~7) | (((lane >> 1) ^ row_) & 7); \
        *reinterpret_cast<ushort4*>(WdL + (bf) * 4096 + row_ * 256 + pos_ * 8 + (lane & 1) * 4) = f2bf4(wreg[i]); \
    } } while (0)

#define H_STAGE(tc, bf) do { _Pragma("unroll") for (int i = 0; i < 4; i++) { \
        int j_ = wv * 4 + i; \
        int row_ = 2 * j_ + (lane >> 5); \
        int p_ = lane & 31; \
        int su_ = (p_ & ~7) | ((p_ ^ row_) & 7); \
        int tok_ = toks_s[row_]; if (tok_ < 0) tok_ = 0; \
        gload16(hin + (size_t)tok_ * H_DIM + (tc) * 256 + su_ * 8, (void*)(Hl + (bf) * 8192 + j_ * 512)); \
    } } while (0)

    f32x4 ac0 = {0,0,0,0}, ac1 = {0,0,0,0};
#define COMPUTE(bf) do { _Pragma("unroll") for (int k32 = 0; k32 < 2; k32++) { \
        int ku_ = wv * 8 + k32 * 4 + kg; \
        int up_ = (ku_ & ~7) | ((ku_ ^ lc) & 7); \
        short8 a0_ = *reinterpret_cast<const short8*>(Hl + (bf) * 8192 + lc * 256 + up_ * 8); \
        short8 a1_ = *reinterpret_cast<const short8*>(Hl + (bf) * 8192 + (16 + lc) * 256 + up_ * 8); \
        short8 bd_ = *reinterpret_cast<const short8*>(WdL + (bf) * 4096 + lc * 256 + up_ * 8); \
        ac0 = MFMA(a0_, bd_, ac0); ac1 = MFMA(a1_, bd_, ac1); \
    } } while (0)

    // prologue
    W_LOAD(0);            // vm 4
    H_STAGE(0, 0);        // vm 8
    VMWAIT(4);            // W0 ready
    W_WRITE(0);
    W_LOAD(1);            // vm <= 8
    H_STAGE(1, 1);        // vm <= 12
    LGKWAIT();
    VMWAIT(8);            // H0 landed (W1+H1 fly)
    BAR();

#pragma unroll
    for (int t = 0; t < 8; t++) {
        COMPUTE(t & 1);
        if (t < 7) {
            VMWAIT(4);
            W_WRITE((t + 1) & 1);
            if (t < 6) W_LOAD(t + 2);
            LGKWAIT();
        }
        BAR();
        if (t < 6) H_STAGE(t + 2, t & 1);
        if (t < 6)      { VMWAIT(8); }
        else if (t == 6){ VMWAIT(0); }
        BAR();
    }

    // epilogue: reduce over 4 waves (alias buf0 of Hl) + store
    f32x4* red = (f32x4*)smem;           // [4 wv][2 frag][64 lane]
    red[(wv * 2 + 0) * 64 + lane] = ac0;
    red[(wv * 2 + 1) * 64 + lane] = ac1;
    __syncthreads();
    if (tid < 128) {
        const int m = tid >> 6, ln = tid & 63, lc_ = ln & 15, kg_ = ln >> 4;
        f32x4 s = red[(0 + m) * 64 + ln];
        s += red[(2 + m) * 64 + ln];
        s += red[(4 + m) * 64 + ln];
        s += red[(6 + m) * 64 + ln];
        float* __restrict__ outp = sh ? yspart : y;
#pragma unroll
        for (int j = 0; j < 4; j++) {
            int tok = toks_s[m * 16 + kg_ * 4 + j];
            if (tok >= 0) outp[(size_t)tok * C_DIM + c0 + lc_] = s[j];
        }
    }
#undef W_LOAD
#undef W_WRITE
#undef H_STAGE
#undef COMPUTE
}

__global__ __launch_bounds__(256) void add_kernel(float* __restrict__ y, const float* __restrict__ ys)
{
    int i = blockIdx.x * 256 + threadIdx.x;
    float4 a = reinterpret_cast<float4*>(y)[i];
    float4 b = reinterpret_cast<const float4*>(ys)[i];
    a.x += b.x; a.y += b.y; a.z += b.z; a.w += b.w;
    reinterpret_cast<float4*>(y)[i] = a;
}

extern "C" void kernel_launch(void* const* d_in, const int* in_sizes, int n_in,
                              void* d_out, int out_size, void* d_ws, size_t ws_size,
                              hipStream_t stream)
{
    const float* x        = (const float*)d_in[0];
    const float* up       = (const float*)d_in[1];
    const float* gate     = (const float*)d_in[2];
    const float* dwn      = (const float*)d_in[3];
    const float* router   = (const float*)d_in[4];
    const float* w_up_s   = (const float*)d_in[5];
    const float* w_gate_s = (const float*)d_in[6];
    const float* w_down_s = (const float*)d_in[7];

    char* ws = (char*)d_ws;
    int* cnt      = (int*)(ws + WS_CNT);
    int* list     = (int*)(ws + WS_LIST);
    ushort* xbf   = (ushort*)(ws + WS_XBF);
    ushort* hbuf  = (ushort*)(ws + WS_HBUF);
    ushort* hsbuf = (ushort*)(ws + WS_HSBUF);
    float* yspart = (float*)(ws + WS_YS);
    float* y = (float*)d_out;

    hipMemsetAsync(cnt, 0, E_NUM * sizeof(int), stream);
    router_kernel<<<T_TOK, 256, 0, stream>>>(x, router, cnt, list, xbf);
    ug_mfma<<<dim3(E_NUM + 1, H_DIM / 16, 8), 256, 0, stream>>>(
        xbf, up, gate, w_up_s, w_gate_s, cnt, list, hbuf, hsbuf);
    down_mfma<<<dim3(E_NUM + 1, C_DIM / 16, 8), 256, 0, stream>>>(
        dwn, w_down_s, hbuf, hsbuf, cnt, list, y, yspart);
    add_kernel<<<(T_TOK * C_DIM / 4) / 256, 256, 0, stream>>>(y, yspart);
}